// Round 6
// baseline (1056.026 us; speedup 1.0000x reference)
//
#include <hip/hip_runtime.h>
#include <hip/hip_cooperative_groups.h>

namespace cg = cooperative_groups;

// Shapes fixed by setup_inputs(): B=4, L=2048, D=2048. All I/O fp32.
#define BB 4
#define LL 2048
#define DD 2048
#define DTC 0.01f
#define NCHUNK 256   // L / CH
#define CH 8
#define NBLK 2048    // cooperative grid: 8 blocks/CU on 256 CUs

// ================== fused cooperative kernel ==================
// __launch_bounds__(256, 8): 8 waves/EU -> VGPR cap 64 -> 8 blocks/CU
// co-residency, required for grid.sync().
__global__ __launch_bounds__(256, 8) void k_all(
        const float* __restrict__ x, const float* __restrict__ jup,
        const float* __restrict__ rdiag, const float* __restrict__ hproj,
        const float* __restrict__ coeffs, float* __restrict__ out,
        float* __restrict__ ws) {
    cg::grid_group grid = cg::this_grid();
    float* xsum    = ws;                 // B*D (atomic accum; zeroed in P1)
    float* delta   = ws + BB * DD;       // B*D (atomic accum; zeroed in P1)
    float* gm      = ws + 2 * BB * DD;   // B*D (plain store)
    float* partial = ws + 3 * BB * DD;   // NCHUNK*B*D = 8 MB (plain store)

    const int tid = threadIdx.x;
    const int bx  = blockIdx.x;
    const int wave = tid >> 6, lane = tid & 63;
    __shared__ float s[4][BB];
    __shared__ float sred[4];

    // ---- P1: zero xsum+delta (8 floats/block) + stage-1 column partials ----
    {
        if (tid < 2) *(float4*)(ws + bx * 8 + tid * 4) = float4{0.f, 0.f, 0.f, 0.f};
        int c = bx & 255, q = bx >> 8;
        int b = q >> 1, half = q & 1;
        int d0 = half * 1024 + (tid << 2);
        const float* p = x + ((size_t)(b * LL + c * CH)) * DD + d0;
        float4 acc = {0.f, 0.f, 0.f, 0.f};
#pragma unroll
        for (int l = 0; l < CH; l++) {
            float4 v = *(const float4*)(p + (size_t)l * DD);
            acc.x += v.x; acc.y += v.y; acc.z += v.z; acc.w += v.w;
        }
        *(float4*)(partial + ((size_t)(c * BB + b)) * DD + d0) = acc;
    }
    grid.sync();

    // ---- P2: reduce partial over chunks into xsum (blocks 0..63) ----
    if (bx < 64) {
        int d0 = (bx & 1) * 1024 + (tid << 2);
        int b  = (bx >> 1) & 3;
        int c0 = (bx >> 3) * 32;
        float4 acc = {0.f, 0.f, 0.f, 0.f};
#pragma unroll
        for (int cc = 0; cc < 32; cc++) {
            float4 v = *(const float4*)(partial + ((size_t)((c0 + cc) * BB + b)) * DD + d0);
            acc.x += v.x; acc.y += v.y; acc.z += v.z; acc.w += v.w;
        }
        float* dst = xsum + b * DD + d0;
        atomicAdd(dst + 0, acc.x);
        atomicAdd(dst + 1, acc.y);
        atomicAdd(dst + 2, acc.z);
        atomicAdd(dst + 3, acc.w);
    }
    grid.sync();

    // ---- P3: gm[b,i] = (1/L) * sum_j hproj[i,j] * xsum[b,j]; block = row i ----
    {
        int i  = bx;
        int j0 = wave * 512 + lane * 8;
        const float* row = hproj + (size_t)i * DD;
        float4 h0 = *(const float4*)(row + j0);
        float4 h1 = *(const float4*)(row + j0 + 4);
        float acc[BB];
#pragma unroll
        for (int b = 0; b < BB; b++) {
            float4 xa = *(const float4*)(xsum + b * DD + j0);
            float4 xb = *(const float4*)(xsum + b * DD + j0 + 4);
            acc[b] = h0.x*xa.x + h0.y*xa.y + h0.z*xa.z + h0.w*xa.w
                   + h1.x*xb.x + h1.y*xb.y + h1.z*xb.z + h1.w*xb.w;
        }
#pragma unroll
        for (int b = 0; b < BB; b++) {
#pragma unroll
            for (int off = 32; off > 0; off >>= 1) acc[b] += __shfl_down(acc[b], off);
        }
        if (lane == 0) {
#pragma unroll
            for (int b = 0; b < BB; b++) s[wave][b] = acc[b];
        }
        __syncthreads();
        if (tid < BB) {
            int b = tid;
            gm[b * DD + i] = (s[0][b] + s[1][b] + s[2][b] + s[3][b]) * (1.0f / LL);
        }
    }
    grid.sync();

    // ---- P4: delta = DT*((Jup - Jup^T - diag(softplus r)) @ gm) via atomics ----
    {
        // row part: block = row i
        int i  = bx;
        int j0 = wave * 512 + lane * 8;
        const float* row = jup + (size_t)i * DD;
        float4 h0 = *(const float4*)(row + j0);
        float4 h1 = *(const float4*)(row + j0 + 4);
        float acc[BB];
#pragma unroll
        for (int b = 0; b < BB; b++) {
            float4 ga = *(const float4*)(gm + b * DD + j0);
            float4 gb = *(const float4*)(gm + b * DD + j0 + 4);
            acc[b] = h0.x*ga.x + h0.y*ga.y + h0.z*ga.z + h0.w*ga.w
                   + h1.x*gb.x + h1.y*gb.y + h1.z*gb.z + h1.w*gb.w;
        }
#pragma unroll
        for (int b = 0; b < BB; b++) {
#pragma unroll
            for (int off = 32; off > 0; off >>= 1) acc[b] += __shfl_down(acc[b], off);
        }
        if (lane == 0) {
#pragma unroll
            for (int b = 0; b < BB; b++) s[wave][b] = acc[b];
        }
        __syncthreads();
        if (tid < BB) {
            int b = tid;
            float r = log1pf(expf(rdiag[i]));  // softplus
            float t = s[0][b] + s[1][b] + s[2][b] + s[3][b];
            atomicAdd(delta + b * DD + i, DTC * (t - gm[b * DD + i] * r));
        }
        // col part: blocks 0..1023, JT=16 (R5-measured-OK config)
        if (bx < 1024) {
            const int JT = 16;
            int ic = (bx & 7) * 256 + tid;
            int jc = (bx >> 3) * JT;
            float a2[BB] = {0.f, 0.f, 0.f, 0.f};
#pragma unroll
            for (int jj = 0; jj < JT; jj++) {
                float v = jup[(size_t)(jc + jj) * DD + ic];
#pragma unroll
                for (int b = 0; b < BB; b++)
                    a2[b] += gm[b * DD + jc + jj] * v;
            }
#pragma unroll
            for (int b = 0; b < BB; b++) atomicAdd(delta + b * DD + ic, -DTC * a2[b]);
        }
    }
    grid.sync();

    // ---- P5: main pass, 4 rows per block ----
    float c[9];
#pragma unroll
    for (int k = 0; k < 9; k++) c[k] = coeffs[k];
    for (int r = 0; r < 4; r++) {
        int row = bx * 4 + r;           // 0 .. B*L-1
        int b   = row >> 11;            // L = 2048
        int d0  = tid << 3;
        size_t base = (size_t)row * DD + d0;

        float4 va = *(const float4*)(x + base);
        float4 vb = *(const float4*)(x + base + 4);
        const float* dl = delta + b * DD + d0;
        float4 da = *(const float4*)dl;
        float4 db = *(const float4*)(dl + 4);
        float xv[8] = {va.x + da.x, va.y + da.y, va.z + da.z, va.w + da.w,
                       vb.x + db.x, vb.y + db.y, vb.z + db.z, vb.w + db.w};

        float ss = 0.f;
#pragma unroll
        for (int k = 0; k < 8; k++) ss += xv[k] * xv[k];
#pragma unroll
        for (int off = 32; off > 0; off >>= 1) ss += __shfl_down(ss, off);
        if (lane == 0) sred[wave] = ss;
        __syncthreads();
        float total = sred[0] + sred[1] + sred[2] + sred[3];
        __syncthreads();   // sred reused next iteration
        float rinv = rsqrtf(fmaxf(total, 1e-8f));

        float o[8];
#pragma unroll
        for (int k = 0; k < 8; k++) {
            float xn = xv[k] * rinv;
            float tp = 1.0f, tc = xn;
            float rr = c[0] + c[1] * xn;
#pragma unroll
            for (int n = 2; n <= 8; n++) {
                float tn = 2.0f * xn * tc - tp;
                rr += c[n] * tn;
                tp = tc; tc = tn;
            }
            o[k] = xv[k] + 0.1f * rr;
        }
        float4 oa = {o[0], o[1], o[2], o[3]};
        float4 ob = {o[4], o[5], o[6], o[7]};
        *(float4*)(out + base)     = oa;
        *(float4*)(out + base + 4) = ob;
    }
}

// ================== fallback path (R5 kernels, proven) ==================
__global__ __launch_bounds__(256) void k_mean_stage1(
        const float* __restrict__ x, float* __restrict__ partial) {
    int c  = blockIdx.x;
    int b  = blockIdx.z;
    int d0 = blockIdx.y * 1024 + (threadIdx.x << 2);
    const float* p = x + ((size_t)(b * LL + c * CH)) * DD + d0;
    float4 acc = {0.f, 0.f, 0.f, 0.f};
#pragma unroll
    for (int l = 0; l < CH; l++) {
        float4 v = *(const float4*)(p + (size_t)l * DD);
        acc.x += v.x; acc.y += v.y; acc.z += v.z; acc.w += v.w;
    }
    *(float4*)(partial + ((size_t)(c * BB + b)) * DD + d0) = acc;
}

__global__ __launch_bounds__(256) void k_mean_stage2(
        const float* __restrict__ partial, float* __restrict__ xsum) {
    int d0 = blockIdx.x * 1024 + (threadIdx.x << 2);
    int b  = blockIdx.y;
    int c0 = blockIdx.z * 32;
    float4 acc = {0.f, 0.f, 0.f, 0.f};
#pragma unroll
    for (int cc = 0; cc < 32; cc++) {
        float4 v = *(const float4*)(partial + ((size_t)((c0 + cc) * BB + b)) * DD + d0);
        acc.x += v.x; acc.y += v.y; acc.z += v.z; acc.w += v.w;
    }
    float* dst = xsum + b * DD + d0;
    atomicAdd(dst + 0, acc.x);
    atomicAdd(dst + 1, acc.y);
    atomicAdd(dst + 2, acc.z);
    atomicAdd(dst + 3, acc.w);
}

__global__ __launch_bounds__(256) void k_gm(
        const float* __restrict__ hproj,
        const float* __restrict__ xsum, float* __restrict__ gm) {
    int i = blockIdx.x;
    int wave = threadIdx.x >> 6, lane = threadIdx.x & 63;
    int j0 = wave * 512 + lane * 8;
    const float* row = hproj + (size_t)i * DD;
    float4 h0 = *(const float4*)(row + j0);
    float4 h1 = *(const float4*)(row + j0 + 4);
    float acc[BB];
#pragma unroll
    for (int b = 0; b < BB; b++) {
        float4 xa = *(const float4*)(xsum + b * DD + j0);
        float4 xb = *(const float4*)(xsum + b * DD + j0 + 4);
        acc[b] = h0.x*xa.x + h0.y*xa.y + h0.z*xa.z + h0.w*xa.w
               + h1.x*xb.x + h1.y*xb.y + h1.z*xb.z + h1.w*xb.w;
    }
#pragma unroll
    for (int b = 0; b < BB; b++) {
#pragma unroll
        for (int off = 32; off > 0; off >>= 1) acc[b] += __shfl_down(acc[b], off);
    }
    __shared__ float s[4][BB];
    if (lane == 0) {
#pragma unroll
        for (int b = 0; b < BB; b++) s[wave][b] = acc[b];
    }
    __syncthreads();
    if (threadIdx.x < BB) {
        int b = threadIdx.x;
        gm[b * DD + i] = (s[0][b] + s[1][b] + s[2][b] + s[3][b]) * (1.0f / LL);
    }
}

__global__ __launch_bounds__(256) void k_delta(
        const float* __restrict__ jup,
        const float* __restrict__ rdiag,
        const float* __restrict__ gm, float* __restrict__ delta) {
    if (blockIdx.x < DD) {
        int i = blockIdx.x;
        int wave = threadIdx.x >> 6, lane = threadIdx.x & 63;
        int j0 = wave * 512 + lane * 8;
        const float* row = jup + (size_t)i * DD;
        float4 h0 = *(const float4*)(row + j0);
        float4 h1 = *(const float4*)(row + j0 + 4);
        float acc[BB];
#pragma unroll
        for (int b = 0; b < BB; b++) {
            float4 ga = *(const float4*)(gm + b * DD + j0);
            float4 gb = *(const float4*)(gm + b * DD + j0 + 4);
            acc[b] = h0.x*ga.x + h0.y*ga.y + h0.z*ga.z + h0.w*ga.w
                   + h1.x*gb.x + h1.y*gb.y + h1.z*gb.z + h1.w*gb.w;
        }
#pragma unroll
        for (int b = 0; b < BB; b++) {
#pragma unroll
            for (int off = 32; off > 0; off >>= 1) acc[b] += __shfl_down(acc[b], off);
        }
        __shared__ float s[4][BB];
        if (lane == 0) {
#pragma unroll
            for (int b = 0; b < BB; b++) s[wave][b] = acc[b];
        }
        __syncthreads();
        if (threadIdx.x < BB) {
            int b = threadIdx.x;
            float r = log1pf(expf(rdiag[i]));
            float t = s[0][b] + s[1][b] + s[2][b] + s[3][b];
            atomicAdd(delta + b * DD + i, DTC * (t - gm[b * DD + i] * r));
        }
    } else {
        const int JT = 16;
        int cidx = blockIdx.x - DD;
        int i  = (cidx & 7) * 256 + threadIdx.x;
        int j0 = (cidx >> 3) * JT;
        float acc[BB] = {0.f, 0.f, 0.f, 0.f};
#pragma unroll
        for (int jj = 0; jj < JT; jj++) {
            float v = jup[(size_t)(j0 + jj) * DD + i];
#pragma unroll
            for (int b = 0; b < BB; b++)
                acc[b] += gm[b * DD + j0 + jj] * v;
        }
#pragma unroll
        for (int b = 0; b < BB; b++) atomicAdd(delta + b * DD + i, -DTC * acc[b]);
    }
}

__global__ __launch_bounds__(256) void k_main(
        const float* __restrict__ x,
        const float* __restrict__ delta,
        const float* __restrict__ coeffs,
        float* __restrict__ out) {
    int row = blockIdx.x;
    int b   = row >> 11;
    int d0  = threadIdx.x << 3;
    size_t base = (size_t)row * DD + d0;

    float4 va = *(const float4*)(x + base);
    float4 vb = *(const float4*)(x + base + 4);
    const float* dl = delta + b * DD + d0;
    float4 da = *(const float4*)dl;
    float4 db = *(const float4*)(dl + 4);
    float xv[8] = {va.x + da.x, va.y + da.y, va.z + da.z, va.w + da.w,
                   vb.x + db.x, vb.y + db.y, vb.z + db.z, vb.w + db.w};

    float ss = 0.f;
#pragma unroll
    for (int k = 0; k < 8; k++) ss += xv[k] * xv[k];
#pragma unroll
    for (int off = 32; off > 0; off >>= 1) ss += __shfl_down(ss, off);
    __shared__ float sred[4];
    int wid = threadIdx.x >> 6, lane = threadIdx.x & 63;
    if (lane == 0) sred[wid] = ss;
    __syncthreads();
    float total = sred[0] + sred[1] + sred[2] + sred[3];
    float rinv = rsqrtf(fmaxf(total, 1e-8f));

    float c[9];
#pragma unroll
    for (int k = 0; k < 9; k++) c[k] = coeffs[k];

    float o[8];
#pragma unroll
    for (int k = 0; k < 8; k++) {
        float xn = xv[k] * rinv;
        float tp = 1.0f, tc = xn;
        float r = c[0] + c[1] * xn;
#pragma unroll
        for (int n = 2; n <= 8; n++) {
            float tn = 2.0f * xn * tc - tp;
            r += c[n] * tn;
            tp = tc; tc = tn;
        }
        o[k] = xv[k] + 0.1f * r;
    }
    float4 oa = {o[0], o[1], o[2], o[3]};
    float4 ob = {o[4], o[5], o[6], o[7]};
    *(float4*)(out + base)     = oa;
    *(float4*)(out + base + 4) = ob;
}

extern "C" void kernel_launch(void* const* d_in, const int* in_sizes, int n_in,
                              void* d_out, int out_size, void* d_ws, size_t ws_size,
                              hipStream_t stream) {
    (void)in_sizes; (void)n_in; (void)out_size; (void)ws_size;
    const float* x      = (const float*)d_in[0];
    const float* jup    = (const float*)d_in[1];
    const float* rdiag  = (const float*)d_in[2];
    const float* hproj  = (const float*)d_in[3];
    const float* coeffs = (const float*)d_in[4];
    float* out = (float*)d_out;
    float* ws  = (float*)d_ws;

    void* args[] = {(void*)&x, (void*)&jup, (void*)&rdiag, (void*)&hproj,
                    (void*)&coeffs, (void*)&out, (void*)&ws};
    hipError_t err = hipLaunchCooperativeKernel((void*)k_all, dim3(NBLK), dim3(256),
                                                args, 0, stream);
    if (err != hipSuccess) {
        // deterministic fallback: proven R5 multi-kernel path
        float* xsum    = ws;
        float* delta   = ws + BB * DD;
        float* gm      = ws + 2 * BB * DD;
        float* partial = ws + 3 * BB * DD;
        hipMemsetAsync(d_ws, 0, (size_t)(2 * BB * DD) * sizeof(float), stream);
        k_mean_stage1<<<dim3(NCHUNK, 2, BB), 256, 0, stream>>>(x, partial);
        k_mean_stage2<<<dim3(2, BB, 8), 256, 0, stream>>>(partial, xsum);
        k_gm<<<DD, 256, 0, stream>>>(hproj, xsum, gm);
        k_delta<<<DD + DD / 2, 256, 0, stream>>>(jup, rdiag, gm, delta);
        k_main<<<BB * LL, 256, 0, stream>>>(x, delta, coeffs, out);
    }
}